// Round 1
// baseline (179325.928 us; speedup 1.0000x reference)
//
#include <hip/hip_runtime.h>

#define TSEQ 512
#define HID  64
#define BT   8      // batch elements per block
#define NTH  256    // threads per block (= 4H gate rows)

__device__ __forceinline__ float fsig(float x) {
    // 1/(1+exp(-x)) = rcp(1 + exp2(-x*log2e))
    float e = __builtin_amdgcn_exp2f(x * -1.44269504088896340736f);
    return __builtin_amdgcn_rcpf(1.0f + e);
}
__device__ __forceinline__ float ftanh(float x) {
    // tanh(x) = 1 - 2/(1+exp(2x)); exp(2x) = exp2(x*2*log2e)
    float e = __builtin_amdgcn_exp2f(x * 2.88539008177792681472f);
    return 1.0f - 2.0f * __builtin_amdgcn_rcpf(1.0f + e);
}

__global__ __launch_bounds__(NTH, 2)
void lstm2_fused(const float* __restrict__ x,
                 const float* __restrict__ W_ih0, const float* __restrict__ W_hh0,
                 const float* __restrict__ b_ih0, const float* __restrict__ b_hh0,
                 const float* __restrict__ W_ih1, const float* __restrict__ W_hh1,
                 const float* __restrict__ b_ih1, const float* __restrict__ b_hh1,
                 const float* __restrict__ W_fc,  const float* __restrict__ b_fc,
                 float* __restrict__ out)
{
    const int tid = threadIdx.x;      // gate-row j in 0..255 (0..63=i, 64..127=f, 128..191=g, 192..255=o)
    const int b0  = blockIdx.x * BT;  // batch tile base
    const int u   = tid & 63;         // hidden unit
    const int wv  = tid >> 6;         // wave id == gate id in matmul phase, b-offset in update phase

    // ---- register-resident weight rows ----
    float w0[HID], w1i[HID], w1h[HID];
    #pragma unroll
    for (int k4 = 0; k4 < HID/4; ++k4) {
        float4 v = ((const float4*)W_hh0)[tid*(HID/4) + k4];
        w0[4*k4+0]=v.x; w0[4*k4+1]=v.y; w0[4*k4+2]=v.z; w0[4*k4+3]=v.w;
    }
    #pragma unroll
    for (int k4 = 0; k4 < HID/4; ++k4) {
        float4 v = ((const float4*)W_ih1)[tid*(HID/4) + k4];
        w1i[4*k4+0]=v.x; w1i[4*k4+1]=v.y; w1i[4*k4+2]=v.z; w1i[4*k4+3]=v.w;
    }
    #pragma unroll
    for (int k4 = 0; k4 < HID/4; ++k4) {
        float4 v = ((const float4*)W_hh1)[tid*(HID/4) + k4];
        w1h[4*k4+0]=v.x; w1h[4*k4+1]=v.y; w1h[4*k4+2]=v.z; w1h[4*k4+3]=v.w;
    }
    const float4 wx   = ((const float4*)W_ih0)[tid];  // IN=4
    const float bias0 = b_ih0[tid] + b_hh0[tid];
    const float bias1 = b_ih1[tid] + b_hh1[tid];

    __shared__ float h0s[BT][HID];
    __shared__ float h1s[BT][HID];
    __shared__ float gs[4][HID][12];   // [gate][u][b], padded 8->12 (48B rows: 16B-aligned float4 stores)
    __shared__ float4 xs[BT];

    for (int i = tid; i < BT*HID; i += NTH) { (&h0s[0][0])[i] = 0.f; (&h1s[0][0])[i] = 0.f; }
    float c0a = 0.f, c0b = 0.f, c1a = 0.f, c1b = 0.f;

    float4 xreg = {0,0,0,0};
    if (tid < BT) xreg = ((const float4*)x)[(size_t)(b0 + tid) * TSEQ];

    for (int t = 0; t < TSEQ; ++t) {
        if (tid < BT) xs[tid] = xreg;
        __syncthreads();                                   // S0: xs[t], h1s[t-1] visible
        if (tid < BT && t + 1 < TSEQ)
            xreg = ((const float4*)x)[(size_t)(b0 + tid) * TSEQ + (t + 1)];  // prefetch t+1

        // ---- layer 0 gate pre-activations: row tid x 8 batch ----
        float acc[BT];
        #pragma unroll
        for (int b = 0; b < BT; ++b) {
            float4 xv = xs[b];
            float a = fmaf(wx.x, xv.x, bias0);
            a = fmaf(wx.y, xv.y, a);
            a = fmaf(wx.z, xv.z, a);
            a = fmaf(wx.w, xv.w, a);
            acc[b] = a;
        }
        #pragma unroll
        for (int k4 = 0; k4 < HID/4; ++k4) {
            #pragma unroll
            for (int b = 0; b < BT; ++b) {
                float4 hv = *(const float4*)&h0s[b][4*k4];   // wave-broadcast read
                acc[b] = fmaf(w0[4*k4+0], hv.x, acc[b]);
                acc[b] = fmaf(w0[4*k4+1], hv.y, acc[b]);
                acc[b] = fmaf(w0[4*k4+2], hv.z, acc[b]);
                acc[b] = fmaf(w0[4*k4+3], hv.w, acc[b]);
            }
        }
        {
            float va[BT];
            #pragma unroll
            for (int b = 0; b < BT; ++b) va[b] = (wv == 2) ? ftanh(acc[b]) : fsig(acc[b]);
            float4 s0 = {va[0],va[1],va[2],va[3]}, s1 = {va[4],va[5],va[6],va[7]};
            *(float4*)&gs[wv][u][0] = s0;
            *(float4*)&gs[wv][u][4] = s1;
        }
        __syncthreads();                                   // S1: gates0 ready

        // ---- layer 0 state update: thread owns (b=wv,u) and (b=4+wv,u) ----
        {
            int b = wv;
            float ig = gs[0][u][b], fg = gs[1][u][b], gg = gs[2][u][b], og = gs[3][u][b];
            c0a = fmaf(fg, c0a, ig * gg);
            h0s[b][u] = og * ftanh(c0a);
            b = 4 + wv;
            ig = gs[0][u][b]; fg = gs[1][u][b]; gg = gs[2][u][b]; og = gs[3][u][b];
            c0b = fmaf(fg, c0b, ig * gg);
            h0s[b][u] = og * ftanh(c0b);
        }
        __syncthreads();                                   // S2: h0s[t] ready

        // ---- layer 1 gate pre-activations: concat(h0_new, h1_prev) dot 128 ----
        #pragma unroll
        for (int b = 0; b < BT; ++b) acc[b] = bias1;
        #pragma unroll
        for (int k4 = 0; k4 < HID/4; ++k4) {
            #pragma unroll
            for (int b = 0; b < BT; ++b) {
                float4 h0v = *(const float4*)&h0s[b][4*k4];
                float4 h1v = *(const float4*)&h1s[b][4*k4];
                acc[b] = fmaf(w1i[4*k4+0], h0v.x, acc[b]);
                acc[b] = fmaf(w1i[4*k4+1], h0v.y, acc[b]);
                acc[b] = fmaf(w1i[4*k4+2], h0v.z, acc[b]);
                acc[b] = fmaf(w1i[4*k4+3], h0v.w, acc[b]);
                acc[b] = fmaf(w1h[4*k4+0], h1v.x, acc[b]);
                acc[b] = fmaf(w1h[4*k4+1], h1v.y, acc[b]);
                acc[b] = fmaf(w1h[4*k4+2], h1v.z, acc[b]);
                acc[b] = fmaf(w1h[4*k4+3], h1v.w, acc[b]);
            }
        }
        {
            float va[BT];
            #pragma unroll
            for (int b = 0; b < BT; ++b) va[b] = (wv == 2) ? ftanh(acc[b]) : fsig(acc[b]);
            float4 s0 = {va[0],va[1],va[2],va[3]}, s1 = {va[4],va[5],va[6],va[7]};
            *(float4*)&gs[wv][u][0] = s0;
            *(float4*)&gs[wv][u][4] = s1;
        }
        __syncthreads();                                   // S3: gates1 ready

        // ---- layer 1 state update ----
        {
            int b = wv;
            float ig = gs[0][u][b], fg = gs[1][u][b], gg = gs[2][u][b], og = gs[3][u][b];
            c1a = fmaf(fg, c1a, ig * gg);
            h1s[b][u] = og * ftanh(c1a);
            b = 4 + wv;
            ig = gs[0][u][b]; fg = gs[1][u][b]; gg = gs[2][u][b]; og = gs[3][u][b];
            c1b = fmaf(fg, c1b, ig * gg);
            h1s[b][u] = og * ftanh(c1b);
        }
        // next-iteration S0 orders h1s writes vs. reads
    }
    __syncthreads();

    // ---- final FC: out[b] = dot(h1_last[b,:], W_fc) + b_fc ----
    const float wfc = W_fc[u];
    #pragma unroll
    for (int p = 0; p < 2; ++p) {
        int b = p*4 + wv;                 // wave wv handles b=wv and b=4+wv
        float part = h1s[b][u] * wfc;
        #pragma unroll
        for (int off = 32; off > 0; off >>= 1) part += __shfl_xor(part, off);
        if (u == 0) out[b0 + b] = part + b_fc[0];
    }
}

extern "C" void kernel_launch(void* const* d_in, const int* in_sizes, int n_in,
                              void* d_out, int out_size, void* d_ws, size_t ws_size,
                              hipStream_t stream) {
    const float* x     = (const float*)d_in[0];
    const float* W_ih0 = (const float*)d_in[1];
    const float* W_hh0 = (const float*)d_in[2];
    const float* b_ih0 = (const float*)d_in[3];
    const float* b_hh0 = (const float*)d_in[4];
    const float* W_ih1 = (const float*)d_in[5];
    const float* W_hh1 = (const float*)d_in[6];
    const float* b_ih1 = (const float*)d_in[7];
    const float* b_hh1 = (const float*)d_in[8];
    const float* W_fc  = (const float*)d_in[9];
    const float* b_fc  = (const float*)d_in[10];
    float* out = (float*)d_out;

    dim3 grid(4096 / BT), block(NTH);
    hipLaunchKernelGGL(lstm2_fused, grid, block, 0, stream,
                       x, W_ih0, W_hh0, b_ih0, b_hh0,
                       W_ih1, W_hh1, b_ih1, b_hh1, W_fc, b_fc, out);
}

// Round 2
// 115991.028 us; speedup vs baseline: 1.5460x; 1.5460x over previous
//
#include <hip/hip_runtime.h>

#define TSEQ 512
#define HID  64
#define BT   8      // batch elements per block
#define NTH  256    // threads per block (= 4H gate rows)

__device__ __forceinline__ float fsig(float x) {
    float e = __builtin_amdgcn_exp2f(x * -1.44269504088896340736f);
    return __builtin_amdgcn_rcpf(1.0f + e);
}
__device__ __forceinline__ float ftanh(float x) {
    float e = __builtin_amdgcn_exp2f(x * 2.88539008177792681472f);
    return 1.0f - 2.0f * __builtin_amdgcn_rcpf(1.0f + e);
}

// launch_bounds(256,1): VGPR budget 512/thread under either arg-2 semantics.
// Round-1 failure: (256,2) -> 128 VGPRs + 192-float weight arrays spilled to
// scratch -> 565 GB HBM traffic/dispatch, 179 ms. Weights MUST be in registers.
__global__ __launch_bounds__(NTH, 1)
void lstm2_fused(const float* __restrict__ x,
                 const float* __restrict__ W_ih0, const float* __restrict__ W_hh0,
                 const float* __restrict__ b_ih0, const float* __restrict__ b_hh0,
                 const float* __restrict__ W_ih1, const float* __restrict__ W_hh1,
                 const float* __restrict__ b_ih1, const float* __restrict__ b_hh1,
                 const float* __restrict__ W_fc,  const float* __restrict__ b_fc,
                 float* __restrict__ out)
{
    const int tid = threadIdx.x;      // gate-row j in 0..255 (0..63=i, 64..127=f, 128..191=g, 192..255=o)
    const int b0  = blockIdx.x * BT;  // batch tile base
    const int u   = tid & 63;         // hidden unit
    const int wv  = tid >> 6;         // wave id == gate id in matmul phase, b-offset in update phase

    // ---- register-resident weight rows ----
    float w0[HID], w1i[HID], w1h[HID];
    #pragma unroll 16
    for (int k4 = 0; k4 < HID/4; ++k4) {
        float4 v = ((const float4*)W_hh0)[tid*(HID/4) + k4];
        w0[4*k4+0]=v.x; w0[4*k4+1]=v.y; w0[4*k4+2]=v.z; w0[4*k4+3]=v.w;
    }
    #pragma unroll 16
    for (int k4 = 0; k4 < HID/4; ++k4) {
        float4 v = ((const float4*)W_ih1)[tid*(HID/4) + k4];
        w1i[4*k4+0]=v.x; w1i[4*k4+1]=v.y; w1i[4*k4+2]=v.z; w1i[4*k4+3]=v.w;
    }
    #pragma unroll 16
    for (int k4 = 0; k4 < HID/4; ++k4) {
        float4 v = ((const float4*)W_hh1)[tid*(HID/4) + k4];
        w1h[4*k4+0]=v.x; w1h[4*k4+1]=v.y; w1h[4*k4+2]=v.z; w1h[4*k4+3]=v.w;
    }
    const float4 wx   = ((const float4*)W_ih0)[tid];  // IN=4
    const float bias0 = b_ih0[tid] + b_hh0[tid];
    const float bias1 = b_ih1[tid] + b_hh1[tid];

    __shared__ float h0s[BT][HID];
    __shared__ float h1s[BT][HID];
    __shared__ float gs[4][BT][HID];   // [gate][b][u]: scalar r/w, lanes stride-1 -> conflict-free
    __shared__ float4 xs[BT];

    for (int i = tid; i < BT*HID; i += NTH) { (&h0s[0][0])[i] = 0.f; (&h1s[0][0])[i] = 0.f; }
    float c0a = 0.f, c0b = 0.f, c1a = 0.f, c1b = 0.f;

    float4 xreg = {0,0,0,0};
    if (tid < BT) xreg = ((const float4*)x)[(size_t)(b0 + tid) * TSEQ];

    for (int t = 0; t < TSEQ; ++t) {
        if (tid < BT) xs[tid] = xreg;
        __syncthreads();                                   // S0: xs[t], h1s[t-1] visible
        if (tid < BT && t + 1 < TSEQ)
            xreg = ((const float4*)x)[(size_t)(b0 + tid) * TSEQ + (t + 1)];  // prefetch t+1

        // ---- layer 0 gate pre-activations: row tid x 8 batch ----
        float acc[BT];
        #pragma unroll 8
        for (int b = 0; b < BT; ++b) {
            float4 xv = xs[b];
            float a = fmaf(wx.x, xv.x, bias0);
            a = fmaf(wx.y, xv.y, a);
            a = fmaf(wx.z, xv.z, a);
            a = fmaf(wx.w, xv.w, a);
            acc[b] = a;
        }
        #pragma unroll 16
        for (int k4 = 0; k4 < HID/4; ++k4) {
            #pragma unroll 8
            for (int b = 0; b < BT; ++b) {
                float4 hv = *(const float4*)&h0s[b][4*k4];   // wave-broadcast read
                acc[b] = fmaf(w0[4*k4+0], hv.x, acc[b]);
                acc[b] = fmaf(w0[4*k4+1], hv.y, acc[b]);
                acc[b] = fmaf(w0[4*k4+2], hv.z, acc[b]);
                acc[b] = fmaf(w0[4*k4+3], hv.w, acc[b]);
            }
        }
        #pragma unroll 8
        for (int b = 0; b < BT; ++b)
            gs[wv][b][u] = (wv == 2) ? ftanh(acc[b]) : fsig(acc[b]);
        __syncthreads();                                   // S1: gates0 ready

        // ---- layer 0 state update: thread owns (b=wv,u) and (b=4+wv,u) ----
        {
            int b = wv;
            float ig = gs[0][b][u], fg = gs[1][b][u], gg = gs[2][b][u], og = gs[3][b][u];
            c0a = fmaf(fg, c0a, ig * gg);
            h0s[b][u] = og * ftanh(c0a);
            b = 4 + wv;
            ig = gs[0][b][u]; fg = gs[1][b][u]; gg = gs[2][b][u]; og = gs[3][b][u];
            c0b = fmaf(fg, c0b, ig * gg);
            h0s[b][u] = og * ftanh(c0b);
        }
        __syncthreads();                                   // S2: h0s[t] ready

        // ---- layer 1 gate pre-activations: concat(h0_new, h1_prev) dot 128 ----
        #pragma unroll 8
        for (int b = 0; b < BT; ++b) acc[b] = bias1;
        #pragma unroll 16
        for (int k4 = 0; k4 < HID/4; ++k4) {
            #pragma unroll 8
            for (int b = 0; b < BT; ++b) {
                float4 h0v = *(const float4*)&h0s[b][4*k4];
                float4 h1v = *(const float4*)&h1s[b][4*k4];
                acc[b] = fmaf(w1i[4*k4+0], h0v.x, acc[b]);
                acc[b] = fmaf(w1i[4*k4+1], h0v.y, acc[b]);
                acc[b] = fmaf(w1i[4*k4+2], h0v.z, acc[b]);
                acc[b] = fmaf(w1i[4*k4+3], h0v.w, acc[b]);
                acc[b] = fmaf(w1h[4*k4+0], h1v.x, acc[b]);
                acc[b] = fmaf(w1h[4*k4+1], h1v.y, acc[b]);
                acc[b] = fmaf(w1h[4*k4+2], h1v.z, acc[b]);
                acc[b] = fmaf(w1h[4*k4+3], h1v.w, acc[b]);
            }
        }
        #pragma unroll 8
        for (int b = 0; b < BT; ++b)
            gs[wv][b][u] = (wv == 2) ? ftanh(acc[b]) : fsig(acc[b]);
        __syncthreads();                                   // S3: gates1 ready

        // ---- layer 1 state update ----
        {
            int b = wv;
            float ig = gs[0][b][u], fg = gs[1][b][u], gg = gs[2][b][u], og = gs[3][b][u];
            c1a = fmaf(fg, c1a, ig * gg);
            h1s[b][u] = og * ftanh(c1a);
            b = 4 + wv;
            ig = gs[0][b][u]; fg = gs[1][b][u]; gg = gs[2][b][u]; og = gs[3][b][u];
            c1b = fmaf(fg, c1b, ig * gg);
            h1s[b][u] = og * ftanh(c1b);
        }
        // next-iteration S0 orders h1s writes vs. reads
    }
    __syncthreads();

    // ---- final FC: out[b] = dot(h1_last[b,:], W_fc) + b_fc ----
    const float wfc = W_fc[u];
    #pragma unroll
    for (int p = 0; p < 2; ++p) {
        int b = p*4 + wv;                 // wave wv handles b=wv and b=4+wv
        float part = h1s[b][u] * wfc;
        #pragma unroll
        for (int off = 32; off > 0; off >>= 1) part += __shfl_xor(part, off);
        if (u == 0) out[b0 + b] = part + b_fc[0];
    }
}

extern "C" void kernel_launch(void* const* d_in, const int* in_sizes, int n_in,
                              void* d_out, int out_size, void* d_ws, size_t ws_size,
                              hipStream_t stream) {
    const float* x     = (const float*)d_in[0];
    const float* W_ih0 = (const float*)d_in[1];
    const float* W_hh0 = (const float*)d_in[2];
    const float* b_ih0 = (const float*)d_in[3];
    const float* b_hh0 = (const float*)d_in[4];
    const float* W_ih1 = (const float*)d_in[5];
    const float* W_hh1 = (const float*)d_in[6];
    const float* b_ih1 = (const float*)d_in[7];
    const float* b_hh1 = (const float*)d_in[8];
    const float* W_fc  = (const float*)d_in[9];
    const float* b_fc  = (const float*)d_in[10];
    float* out = (float*)d_out;

    dim3 grid(4096 / BT), block(NTH);
    hipLaunchKernelGGL(lstm2_fused, grid, block, 0, stream,
                       x, W_ih0, W_hh0, b_ih0, b_hh0,
                       W_ih1, W_hh1, b_ih1, b_hh1, W_fc, b_fc, out);
}

// Round 3
// 654.949 us; speedup vs baseline: 273.8014x; 177.0994x over previous
//
#include <hip/hip_runtime.h>

#define TSEQ 512
#define HID  64
#define BT   16     // batch per block (= MFMA N)
#define NTH  512    // 8 waves: 0-3 layer0, 4-7 layer1

typedef __attribute__((ext_vector_type(8))) short short8;
typedef __attribute__((ext_vector_type(4))) float f32x4;
typedef __attribute__((ext_vector_type(4))) unsigned int u32x4;

__device__ __forceinline__ float fsig(float x) {
    float e = __builtin_amdgcn_exp2f(x * -1.44269504088896340736f);
    return __builtin_amdgcn_rcpf(1.0f + e);
}
__device__ __forceinline__ float ftanh(float x) {
    float e = __builtin_amdgcn_exp2f(x * 2.88539008177792681472f);
    return 1.0f - 2.0f * __builtin_amdgcn_rcpf(1.0f + e);
}

// round f32 -> bf16 (RNE), return 16-bit pattern
__device__ __forceinline__ unsigned rne16(float f) {
    unsigned u = __builtin_bit_cast(unsigned, f);
    return ((u + 0x7fffu + ((u >> 16) & 1u)) >> 16) & 0xffffu;
}
// pack f32 as (hi-bf16<<16) | lo-bf16, hi = truncation, lo = rne(f - hi)
__device__ __forceinline__ unsigned packhl(float f) {
    unsigned u  = __builtin_bit_cast(unsigned, f);
    unsigned hb = u & 0xffff0000u;
    float lof   = f - __builtin_bit_cast(float, hb);
    return hb | rne16(lof);
}
// build hi/lo bf16x8 fragments from 8 packed words (element e <-> k-offset e)
__device__ __forceinline__ void mkBfrag(const unsigned q[8], short8* fhi, short8* flo) {
    u32x4 H, L;
    H.x = (q[0] >> 16) | (q[1] & 0xffff0000u);
    H.y = (q[2] >> 16) | (q[3] & 0xffff0000u);
    H.z = (q[4] >> 16) | (q[5] & 0xffff0000u);
    H.w = (q[6] >> 16) | (q[7] & 0xffff0000u);
    L.x = (q[0] & 0xffffu) | (q[1] << 16);
    L.y = (q[2] & 0xffffu) | (q[3] << 16);
    L.z = (q[4] & 0xffffu) | (q[5] << 16);
    L.w = (q[6] & 0xffffu) | (q[7] << 16);
    *fhi = __builtin_bit_cast(short8, H);
    *flo = __builtin_bit_cast(short8, L);
}
// split 8 f32 weights into hi/lo fragments
__device__ __forceinline__ void packA(const float w8[8], short8* fhi, short8* flo) {
    unsigned hw[8], lw[8];
    #pragma unroll
    for (int e = 0; e < 8; ++e) {
        unsigned u  = __builtin_bit_cast(unsigned, w8[e]);
        unsigned hb = u & 0xffff0000u;
        hw[e] = u >> 16;
        lw[e] = rne16(w8[e] - __builtin_bit_cast(float, hb));
    }
    u32x4 H = { hw[0] | (hw[1] << 16), hw[2] | (hw[3] << 16),
                hw[4] | (hw[5] << 16), hw[6] | (hw[7] << 16) };
    u32x4 L = { lw[0] | (lw[1] << 16), lw[2] | (lw[3] << 16),
                lw[4] | (lw[5] << 16), lw[6] | (lw[7] << 16) };
    *fhi = __builtin_bit_cast(short8, H);
    *flo = __builtin_bit_cast(short8, L);
}

#define MFMA(a, b, c) __builtin_amdgcn_mfma_f32_16x16x32_bf16((a), (b), (c), 0, 0, 0)

__global__ __launch_bounds__(NTH, 2)
void lstm2_mfma(const float* __restrict__ x,
                const float* __restrict__ W_ih0, const float* __restrict__ W_hh0,
                const float* __restrict__ b_ih0, const float* __restrict__ b_hh0,
                const float* __restrict__ W_ih1, const float* __restrict__ W_hh1,
                const float* __restrict__ b_ih1, const float* __restrict__ b_hh1,
                const float* __restrict__ W_fc,  const float* __restrict__ b_fc,
                float* __restrict__ out)
{
    const int tid  = threadIdx.x;
    const int lane = tid & 63;
    const int wv   = tid >> 6;       // 0-3: layer0, 4-7: layer1
    const int rl   = lane & 15;      // MFMA row/col-local (also batch col n)
    const int g    = lane >> 4;      // k-group 0..3
    const int b0   = blockIdx.x * BT;

    // LDS: h as packed (hi-bf16 | lo-bf16) u32, XOR-swizzled 16B granules.
    __shared__ unsigned h0p[2][16][64];   // [parity][n][k]   granule ^= (n&15)
    __shared__ unsigned h1p[2][16][64];
    __shared__ unsigned xp [2][16][32];   // [parity][n][k]   granule ^= (n&7)
    __shared__ float    fcl[64][16];      // final h1 f32 for FC

    // zero-init LDS
    {
        unsigned* z = (unsigned*)h0p;
        for (int i = tid; i < 2*16*64*2 + 2*16*32; i += NTH) z[i] = 0u;
        float* zf = (float*)fcl;
        for (int i = tid; i < 64*16; i += NTH) zf[i] = 0.f;
    }
    // stage x[0] into xp[0]
    if (tid < 16) {
        const float* xs = x + ((size_t)(b0 + tid) * TSEQ) * 4;
        u32x4 pk = { packhl(xs[0]), packhl(xs[1]), packhl(xs[2]), packhl(xs[3]) };
        *(u32x4*)(&xp[0][tid][((0 ^ (tid & 7)) << 2)]) = pk;
    }
    __syncthreads();

    if (wv < 4) {
        // ================= LAYER 0 role: wave wv handles u in [16*wv, 16*wv+16) ====
        const int w = wv;
        // A fragments: [gate][s][hi/lo]; s=0,1: W_hh0 k=32s.., s=2: W_ih0 (k-local 0..3) + zeros
        short8 A0[4][3][2];
        float  bs[4][4];
        #pragma unroll
        for (int G = 0; G < 4; ++G) {
            const int row = 64*G + 16*w + rl;
            #pragma unroll
            for (int s = 0; s < 3; ++s) {
                float w8[8];
                if (s < 2) {
                    const float* src = W_hh0 + row*64 + s*32 + g*8;
                    #pragma unroll
                    for (int e = 0; e < 8; ++e) w8[e] = src[e];
                } else {
                    #pragma unroll
                    for (int e = 0; e < 8; ++e) w8[e] = 0.f;
                    if (g == 0) {
                        #pragma unroll
                        for (int e = 0; e < 4; ++e) w8[e] = W_ih0[row*4 + e];
                    }
                }
                packA(w8, &A0[G][s][0], &A0[G][s][1]);
            }
            const int rb = 64*G + 16*w + g*4;
            #pragma unroll
            for (int j = 0; j < 4; ++j) bs[G][j] = b_ih0[rb + j] + b_hh0[rb + j];
        }
        float c0[4] = {0.f, 0.f, 0.f, 0.f};

        for (int i = 0; i <= TSEQ; ++i) {
            if (i < TSEQ) {
                const int p = i & 1;
                // prefetch x[i+1]
                f32x4 xf;
                const bool doX = (w == 0) && (lane < 16) && (i + 1 < TSEQ);
                if (doX) xf = *(const f32x4*)(x + ((size_t)(b0 + lane) * TSEQ + (i + 1)) * 4);

                // B fragments: s=0,1 from h0, s=2 from x
                short8 Bh[3], Bl[3];
                unsigned q[8];
                #pragma unroll
                for (int s = 0; s < 2; ++s) {
                    const unsigned* row = &h0p[p][rl][0];
                    int k0 = 32*s + 8*g;
                    int g0 = ((k0 >> 2)     ) ^ (rl & 15);
                    int g1 = ((k0 >> 2) + 1) ^ (rl & 15);
                    u32x4 a = *(const u32x4*)(row + g0*4);
                    u32x4 b = *(const u32x4*)(row + g1*4);
                    q[0]=a.x; q[1]=a.y; q[2]=a.z; q[3]=a.w;
                    q[4]=b.x; q[5]=b.y; q[6]=b.z; q[7]=b.w;
                    mkBfrag(q, &Bh[s], &Bl[s]);
                }
                {
                    const unsigned* row = &xp[p][rl][0];
                    int g0 = ((2*g)    ) ^ (rl & 7);
                    int g1 = ((2*g) + 1) ^ (rl & 7);
                    u32x4 a = *(const u32x4*)(row + g0*4);
                    u32x4 b = *(const u32x4*)(row + g1*4);
                    q[0]=a.x; q[1]=a.y; q[2]=a.z; q[3]=a.w;
                    q[4]=b.x; q[5]=b.y; q[6]=b.z; q[7]=b.w;
                    mkBfrag(q, &Bh[2], &Bl[2]);
                }

                f32x4 acc[4];
                #pragma unroll
                for (int G = 0; G < 4; ++G) {
                    acc[G].x = bs[G][0]; acc[G].y = bs[G][1];
                    acc[G].z = bs[G][2]; acc[G].w = bs[G][3];
                }
                #pragma unroll
                for (int s = 0; s < 3; ++s) {
                    #pragma unroll
                    for (int G = 0; G < 4; ++G) acc[G] = MFMA(A0[G][s][0], Bh[s], acc[G]);
                    #pragma unroll
                    for (int G = 0; G < 4; ++G) acc[G] = MFMA(A0[G][s][0], Bl[s], acc[G]);
                    #pragma unroll
                    for (int G = 0; G < 4; ++G) acc[G] = MFMA(A0[G][s][1], Bh[s], acc[G]);
                }
                // activate + update c/h fully in-register (all 4 gates of (u,n) in-lane)
                u32x4 pk;
                #pragma unroll
                for (int j = 0; j < 4; ++j) {
                    float it = fsig(acc[0][j]), ft = fsig(acc[1][j]);
                    float gt = ftanh(acc[2][j]), ot = fsig(acc[3][j]);
                    c0[j] = ft * c0[j] + it * gt;
                    float h = ot * ftanh(c0[j]);
                    ((unsigned*)&pk)[j] = packhl(h);
                }
                // write h0[i] to ping buffer: granule (4w+g) ^ (n&15)
                *(u32x4*)(&h0p[p ^ 1][rl][(((4*w + g) ^ (rl & 15)) << 2)]) = pk;
                // stage x[i+1]
                if (doX) {
                    u32x4 pkx = { packhl(xf.x), packhl(xf.y), packhl(xf.z), packhl(xf.w) };
                    *(u32x4*)(&xp[p ^ 1][lane][((0 ^ (lane & 7)) << 2)]) = pkx;
                }
            }
            __syncthreads();
        }
    } else {
        // ================= LAYER 1 role (1-step skew): at iter i computes step i-1 ====
        const int w = wv - 4;
        // A fragments: [gate][s][hi/lo]; s=0,1: W_ih1 (vs h0), s=2,3: W_hh1 (vs h1)
        short8 A1[4][4][2];
        float  bs[4][4];
        #pragma unroll
        for (int G = 0; G < 4; ++G) {
            const int row = 64*G + 16*w + rl;
            #pragma unroll
            for (int s = 0; s < 4; ++s) {
                float w8[8];
                const float* src = (s < 2) ? (W_ih1 + row*64 + s*32 + g*8)
                                           : (W_hh1 + row*64 + (s-2)*32 + g*8);
                #pragma unroll
                for (int e = 0; e < 8; ++e) w8[e] = src[e];
                packA(w8, &A1[G][s][0], &A1[G][s][1]);
            }
            const int rb = 64*G + 16*w + g*4;
            #pragma unroll
            for (int j = 0; j < 4; ++j) bs[G][j] = b_ih1[rb + j] + b_hh1[rb + j];
        }
        float c1[4] = {0.f, 0.f, 0.f, 0.f};

        for (int i = 0; i <= TSEQ; ++i) {
            if (i > 0) {
                const int p = i & 1;
                short8 Bh[4], Bl[4];
                unsigned q[8];
                #pragma unroll
                for (int s = 0; s < 4; ++s) {
                    const unsigned* row = (s < 2) ? &h0p[p][rl][0] : &h1p[p][rl][0];
                    int k0 = 32*(s & 1) + 8*g;
                    int g0 = ((k0 >> 2)     ) ^ (rl & 15);
                    int g1 = ((k0 >> 2) + 1) ^ (rl & 15);
                    u32x4 a = *(const u32x4*)(row + g0*4);
                    u32x4 b = *(const u32x4*)(row + g1*4);
                    q[0]=a.x; q[1]=a.y; q[2]=a.z; q[3]=a.w;
                    q[4]=b.x; q[5]=b.y; q[6]=b.z; q[7]=b.w;
                    mkBfrag(q, &Bh[s], &Bl[s]);
                }

                f32x4 acc[4];
                #pragma unroll
                for (int G = 0; G < 4; ++G) {
                    acc[G].x = bs[G][0]; acc[G].y = bs[G][1];
                    acc[G].z = bs[G][2]; acc[G].w = bs[G][3];
                }
                #pragma unroll
                for (int s = 0; s < 4; ++s) {
                    #pragma unroll
                    for (int G = 0; G < 4; ++G) acc[G] = MFMA(A1[G][s][0], Bh[s], acc[G]);
                    #pragma unroll
                    for (int G = 0; G < 4; ++G) acc[G] = MFMA(A1[G][s][0], Bl[s], acc[G]);
                    #pragma unroll
                    for (int G = 0; G < 4; ++G) acc[G] = MFMA(A1[G][s][1], Bh[s], acc[G]);
                }
                u32x4 pk;
                float hj[4];
                #pragma unroll
                for (int j = 0; j < 4; ++j) {
                    float it = fsig(acc[0][j]), ft = fsig(acc[1][j]);
                    float gt = ftanh(acc[2][j]), ot = fsig(acc[3][j]);
                    c1[j] = ft * c1[j] + it * gt;
                    hj[j] = ot * ftanh(c1[j]);
                    ((unsigned*)&pk)[j] = packhl(hj[j]);
                }
                *(u32x4*)(&h1p[p ^ 1][rl][(((4*w + g) ^ (rl & 15)) << 2)]) = pk;
                if (i == TSEQ) {   // h1[511] in f32 for the FC epilogue
                    #pragma unroll
                    for (int j = 0; j < 4; ++j) fcl[16*w + 4*g + j][rl] = hj[j];
                }
            }
            __syncthreads();
        }
    }

    // ---- FC: out[b] = h1_last[b,:] . W_fc + b_fc ----
    if (tid < 16) {
        float acc = b_fc[0];
        #pragma unroll 16
        for (int u = 0; u < 64; ++u) acc += fcl[u][tid] * W_fc[u];
        out[b0 + tid] = acc;
    }
}

extern "C" void kernel_launch(void* const* d_in, const int* in_sizes, int n_in,
                              void* d_out, int out_size, void* d_ws, size_t ws_size,
                              hipStream_t stream) {
    const float* x     = (const float*)d_in[0];
    const float* W_ih0 = (const float*)d_in[1];
    const float* W_hh0 = (const float*)d_in[2];
    const float* b_ih0 = (const float*)d_in[3];
    const float* b_hh0 = (const float*)d_in[4];
    const float* W_ih1 = (const float*)d_in[5];
    const float* W_hh1 = (const float*)d_in[6];
    const float* b_ih1 = (const float*)d_in[7];
    const float* b_hh1 = (const float*)d_in[8];
    const float* W_fc  = (const float*)d_in[9];
    const float* b_fc  = (const float*)d_in[10];
    float* out = (float*)d_out;

    dim3 grid(4096 / BT), block(NTH);
    hipLaunchKernelGGL(lstm2_mfma, grid, block, 0, stream,
                       x, W_ih0, W_hh0, b_ih0, b_hh0,
                       W_ih1, W_hh1, b_ih1, b_hh1, W_fc, b_fc, out);
}